// Round 1
// baseline (29673.187 us; speedup 1.0000x reference)
//
#include <hip/hip_runtime.h>

#define N_STEPS 100000
#define TAPS 32
#define NDIMS 2
#define ELEMS 64              // taps*dims complex elements per step
#define LR_W 0.0625f          // 1/2^4
#define LR_F 0.0078125f       // 1/2^7
#define LR_B 0.00048828125f   // 1/2^11
#define GMAXF 30.0f
#define EPS_C 1e-8f
#define HALF_S10 1.58113883f  // sqrt(10)/2
#define INV_S10 0.316227766f  // 1/sqrt(10)

__device__ inline float allsum64(float x) {
    x += __shfl_xor(x, 1);
    x += __shfl_xor(x, 2);
    x += __shfl_xor(x, 4);
    x += __shfl_xor(x, 8);
    x += __shfl_xor(x, 16);
    x += __shfl_xor(x, 32);
    return x;
}

// Parallel precompute: per step n
//   kappa[n] = LR_W / (sum|u_n|^2 + eps)
//   krho1[n] = kappa[n] * sum conj(u_n)*u_{n+1}
//   krho2[n] = kappa[n] * sum conj(u_n)*u_{n+2}
__global__ __launch_bounds__(256) void ddlms_pre(const float2* __restrict__ u,
                                                 float4* __restrict__ A,
                                                 float2* __restrict__ B) {
    const int wave = threadIdx.x >> 6;
    const int lane = threadIdx.x & 63;
    const int n = blockIdx.x * 4 + wave;
    if (n >= N_STEPS) return;
    const int n1 = min(n + 1, N_STEPS - 1);
    const int n2 = min(n + 2, N_STEPS - 1);
    float2 u0 = u[(size_t)n  * ELEMS + lane];
    float2 u1 = u[(size_t)n1 * ELEMS + lane];
    float2 u2 = u[(size_t)n2 * ELEMS + lane];
    float su  = u0.x * u0.x + u0.y * u0.y;
    float r1r = u0.x * u1.x + u0.y * u1.y;   // conj(u0)*u1
    float r1i = u0.x * u1.y - u0.y * u1.x;
    float r2r = u0.x * u2.x + u0.y * u2.y;   // conj(u0)*u2
    float r2i = u0.x * u2.y - u0.y * u2.x;
    su  = allsum64(su);
    r1r = allsum64(r1r);
    r1i = allsum64(r1i);
    r2r = allsum64(r2r);
    r2i = allsum64(r2i);
    if (lane == 0) {
        float kappa = LR_W / (su + EPS_C);   // exact: LR_W is a power of two
        A[n] = make_float4(kappa, kappa * r1r, kappa * r1i, 0.0f);
        B[n] = make_float2(kappa * r2r, kappa * r2i);
    }
}

// Serial scan. One wave (64 lanes) per output dim; lane l owns w[dim][j=l&1][t=l>>1]
// (flat element e = l matches u's [taps][dims] layout).
__global__ __launch_bounds__(64) void ddlms_main(const float2* __restrict__ uin,
                                                 const float4* __restrict__ A,
                                                 const float2* __restrict__ B,
                                                 float2* __restrict__ out) {
    const int dim  = blockIdx.x;    // 0 or 1
    const int lane = threadIdx.x;   // 0..63

    // per-lane w element
    float wr = 0.0f, wi = 0.0f;
    // replicated scalar state
    float vr = 0.0f, vi = 0.0f;     // v_n
    float fr = 1.0f, fi = 0.0f;     // f_n
    float br = 0.0f, bi = 0.0f;     // b_n
    float psir = 1.0f, psii = 0.0f; // conj(f_n)/|f_n|
    // reduction pipeline (2-iteration latency): stage-1-reduced products of w_{n-1}*u_{n+1}
    float redr = 0.0f, redi = 0.0f;
    // carry: krho2[n-1]*e_w_{n-1}
    float vpr = 0.0f, vpi = 0.0f;

    // u ring buffer: at start of iter n, ubuf[(n+k)&7] = u[n+k] for k=1..8
    float2 ubuf[8];
    float2 uc = uin[lane];          // u[0], this lane's element
#pragma unroll
    for (int k = 1; k <= 8; ++k)
        ubuf[k & 7] = uin[(size_t)k * ELEMS + lane];

    // kappa/rho batches: lane l holds step base+l; double buffered
    float4 Areg  = A[lane];
    float2 Breg  = B[lane];
    float4 Anext = A[64 + lane];
    float2 Bnext = B[64 + lane];

    float2* outp = out + dim;       // out viewed as float2[N][NDIMS]

    for (int nb = 0; nb < N_STEPS; nb += 8) {
#pragma unroll
        for (int q = 0; q < 8; ++q) {
            const int n = nb + q;

            // rotate kappa/rho batch every 64 steps
            if ((n & 63) == 0 && n != 0) {
                Areg = Anext;
                Breg = Bnext;
                const int bidx = min(n + 64 + lane, N_STEPS - 1);
                Anext = A[bidx];
                Bnext = B[bidx];
            }
            const int sl = n & 63;
            const float kap = __shfl(Areg.x, sl);
            const float k1r = __shfl(Areg.y, sl);
            const float k1i = __shfl(Areg.z, sl);
            const float k2r = __shfl(Breg.x, sl);
            const float k2i = __shfl(Breg.y, sl);

            // finish reduction started last iter: P2 = sum w_{n-1}*u_{n+1}
            float P2r = redr, P2i = redi;
            P2r += __shfl_xor(P2r, 8);  P2i += __shfl_xor(P2i, 8);
            P2r += __shfl_xor(P2r, 16); P2i += __shfl_xor(P2i, 16);
            P2r += __shfl_xor(P2r, 32); P2i += __shfl_xor(P2i, 32);

            // start new reduction: p = w_n * u[n+2]  (w not yet updated this iter)
            const float2 u2 = ubuf[(q + 2) & 7];
            float pr = wr * u2.x - wi * u2.y;
            float pi = wr * u2.y + wi * u2.x;
            pr += __shfl_xor(pr, 1); pi += __shfl_xor(pi, 1);
            pr += __shfl_xor(pr, 2); pi += __shfl_xor(pi, 2);
            pr += __shfl_xor(pr, 4); pi += __shfl_xor(pi, 4);

            // u rotate + deep prefetch (8 iters ahead)
            const float2 un = ubuf[(q + 1) & 7];
            ubuf[(q + 1) & 7] = uin[(size_t)min(n + 9, N_STEPS - 1) * ELEMS + lane];

            // ---- off-chain v_n-derived helpers ----
            const float m2v  = vr * vr + vi * vi;
            const float invv = __builtin_amdgcn_rcpf(m2v + EPS_C);
            const float cvs  = LR_F * invv;
            const float cvr  = vr * cvs, cvi = -vi * cvs;  // LR_F*conj(v)*invv
            const float Rf   = GMAXF * (m2v + EPS_C) * __builtin_amdgcn_rsqf(m2v);

            // ---- serial chain ----
            // z = v*f + b  (this step's output)
            const float zr = vr * fr - vi * fi + br;
            const float zi = vr * fi + vi * fr + bi;
            if (lane == 0) outp[(size_t)n * NDIMS] = make_float2(zr, zi);

            // d = slice(z): nearest odd level, ties to lower (matches argmin first-index)
            float odr = 2.0f * ceilf(zr * HALF_S10) - 1.0f;
            float odi = 2.0f * ceilf(zi * HALF_S10) - 1.0f;
            odr = fminf(3.0f, fmaxf(-3.0f, odr));
            odi = fminf(3.0f, fmaxf(-3.0f, odi));
            const float dr = odr * INV_S10;
            const float di = odi * INV_S10;

            // e = d - z  (= e_f = e_s = e_b)
            const float er = dr - zr, ei = di - zi;

            // e_w = (d - b_n)*psi_n - v_n
            const float dbr = dr - br, dbi = di - bi;
            const float ewr = dbr * psir - dbi * psii - vr;
            const float ewi = dbr * psii + dbi * psir - vi;

            // b update
            br += LR_B * er;
            bi += LR_B * ei;

            // f update: f += fac * (e * LR_F*conj(v)*invv), fac = clip factor
            const float e2  = er * er + ei * ei;
            const float fac = fminf(1.0f, Rf * __builtin_amdgcn_rsqf(e2));
            const float gr  = er * cvr - ei * cvi;
            const float gi  = er * cvi + ei * cvr;
            fr += fac * gr;
            fi += fac * gi;

            // psi for next step: conj(f_{n+1})/|f_{n+1}|
            const float m2f = fr * fr + fi * fi;
            const float rsf = __builtin_amdgcn_rsqf(m2f);
            psir = fr * rsf;
            psii = -fi * rsf;

            // v_{n+1} = P2 + krho2[n-1]*ew_{n-1} + krho1[n]*ew_n
            vr = P2r + vpr + k1r * ewr - k1i * ewi;
            vi = P2i + vpi + k1r * ewi + k1i * ewr;

            // carry krho2[n]*ew_n for next iter
            vpr = k2r * ewr - k2i * ewi;
            vpi = k2r * ewi + k2i * ewr;

            // w += (kappa*ew) * conj(u_n)   (gw clip provably inactive: |gw| << 30)
            const float mwr = kap * ewr, mwi = kap * ewi;
            wr += mwr * uc.x + mwi * uc.y;
            wi += mwi * uc.x - mwr * uc.y;

            // rotate
            uc = un;
            redr = pr;
            redi = pi;
        }
    }
}

extern "C" void kernel_launch(void* const* d_in, const int* in_sizes, int n_in,
                              void* d_out, int out_size, void* d_ws, size_t ws_size,
                              hipStream_t stream) {
    const float2* u = (const float2*)d_in[0];
    float4* A = (float4*)d_ws;                                        // 1.6 MB
    float2* B = (float2*)((char*)d_ws + (size_t)N_STEPS * sizeof(float4)); // +0.8 MB
    ddlms_pre<<<(N_STEPS + 3) / 4, 256, 0, stream>>>(u, A, B);
    ddlms_main<<<NDIMS, 64, 0, stream>>>(u, A, B, (float2*)d_out);
}

// Round 2
// 22598.563 us; speedup vs baseline: 1.3131x; 1.3131x over previous
//
#include <hip/hip_runtime.h>

#define N_STEPS 100000
#define TAPS 32
#define NDIMS 2
#define ELEMS 64              // taps*dims complex elements per step
#define LR_W 0.0625f          // 1/2^4
#define LR_F 0.0078125f       // 1/2^7
#define LR_B 0.00048828125f   // 1/2^11
#define GMAXF 30.0f
#define EPS_C 1e-8f
#define HALF_S10 1.58113883f  // sqrt(10)/2
#define INV_S10 0.316227766f  // 1/sqrt(10)

// ---- DPP helpers (VALU pipe — no LDS/ds_bpermute, no lgkmcnt stalls) ----
// DPP ctrl: quad_perm xor1 = 0xB1, xor2 = 0x4E; row_half_mirror = 0x141
// (acts as xor4 once quads are uniform); row_mirror = 0x140 (acts as xor8
// once 8-groups are uniform); row_bcast15 = 0x142 (rows 1,3); row_bcast31 =
// 0x143 (rows 2,3).
#define DPPADD(v, ctrl, rmask)                                                   \
    do {                                                                         \
        int _t = __builtin_amdgcn_update_dpp(0, __float_as_int(v), ctrl, rmask,  \
                                             0xF, true);                         \
        (v) += __int_as_float(_t);                                               \
    } while (0)

__device__ inline float allsum64(float x) {   // precompute kernel only
    x += __shfl_xor(x, 1);
    x += __shfl_xor(x, 2);
    x += __shfl_xor(x, 4);
    x += __shfl_xor(x, 8);
    x += __shfl_xor(x, 16);
    x += __shfl_xor(x, 32);
    return x;
}

// Parallel precompute: per step n
//   C[n] = {kappa, kappa*rho1.re, kappa*rho1.im, 0}
//   D[n] = {kappa*rho2.re, kappa*rho2.im}
// kappa[n] = LR_W/(sum|u_n|^2+eps), rho_k = sum conj(u_n)*u_{n+k}
__global__ __launch_bounds__(256) void ddlms_pre(const float2* __restrict__ u,
                                                 float4* __restrict__ C,
                                                 float2* __restrict__ D) {
    const int wave = threadIdx.x >> 6;
    const int lane = threadIdx.x & 63;
    const int n = blockIdx.x * 4 + wave;
    if (n >= N_STEPS) return;
    const int n1 = min(n + 1, N_STEPS - 1);
    const int n2 = min(n + 2, N_STEPS - 1);
    float2 u0 = u[(size_t)n  * ELEMS + lane];
    float2 u1 = u[(size_t)n1 * ELEMS + lane];
    float2 u2 = u[(size_t)n2 * ELEMS + lane];
    float su  = u0.x * u0.x + u0.y * u0.y;
    float r1r = u0.x * u1.x + u0.y * u1.y;   // conj(u0)*u1
    float r1i = u0.x * u1.y - u0.y * u1.x;
    float r2r = u0.x * u2.x + u0.y * u2.y;   // conj(u0)*u2
    float r2i = u0.x * u2.y - u0.y * u2.x;
    su  = allsum64(su);
    r1r = allsum64(r1r);
    r1i = allsum64(r1i);
    r2r = allsum64(r2r);
    r2i = allsum64(r2i);
    if (lane == 0) {
        float kappa = LR_W / (su + EPS_C);
        C[n] = make_float4(kappa, kappa * r1r, kappa * r1i, 0.0f);
        D[n] = make_float2(kappa * r2r, kappa * r2i);
    }
}

// Serial scan. One wave per output dim; lane l owns w element l ([taps][dims] flat).
__global__ __launch_bounds__(64) void ddlms_main(const float2* __restrict__ uin,
                                                 const float4* __restrict__ C,
                                                 const float2* __restrict__ D,
                                                 float2* __restrict__ out) {
    const int dim  = blockIdx.x;    // 0 or 1
    const int lane = threadIdx.x;   // 0..63

    // per-lane w element
    float wr = 0.0f, wi = 0.0f;
    // replicated scalar state
    float vr = 0.0f, vi = 0.0f;     // v_n
    float fr = 1.0f, fi = 0.0f;     // f_n
    float br = 0.0f, bi = 0.0f;     // b_n
    float psir = 1.0f, psii = 0.0f; // conj(f_n)/|f_n|
    // reduction pipeline (2-iter latency): 8-group partial sums of w_{n-1}*u_{n+1}
    float redr = 0.0f, redi = 0.0f;
    // carry: krho2[n-1]*e_w_{n-1}
    float vpr = 0.0f, vpi = 0.0f;

    // u ring buffer: at start of iter n, ubuf[(n+k)&7] = u[n+k] for k=1..8
    float2 ubuf[8];
    float2 uc = uin[lane];          // u[0], this lane's element
#pragma unroll
    for (int k = 1; k <= 8; ++k)
        ubuf[k & 7] = uin[(size_t)k * ELEMS + lane];

    // coefficient ring, 4 steps deep (uniform-address loads; no shfl broadcast)
    float4 creg[4];
    float2 dreg[4];
#pragma unroll
    for (int k = 0; k < 4; ++k) {
        creg[k] = C[k];
        dreg[k] = D[k];
    }

    float2* outp = out + dim;       // out viewed as float2[N][NDIMS]

    for (int nb = 0; nb < N_STEPS; nb += 8) {
#pragma unroll
        for (int q = 0; q < 8; ++q) {
            const int n = nb + q;

            // current-step coefficients, then prefetch step n+4 into same slot
            const float kap = creg[q & 3].x;
            const float k1r = creg[q & 3].y;
            const float k1i = creg[q & 3].z;
            const float k2r = dreg[q & 3].x;
            const float k2i = dreg[q & 3].y;
            {
                const int cn = min(n + 4, N_STEPS - 1);
                creg[q & 3] = C[cn];
                dreg[q & 3] = D[cn];
            }

            // finish reduction started last iter: P2 = sum w_{n-1}*u_{n+1}
            // (redr/redi hold 8-group sums; mirror16 + masked bcasts -> lane63)
            float P2r = redr, P2i = redi;
            DPPADD(P2r, 0x140, 0xF); DPPADD(P2i, 0x140, 0xF);  // row_mirror: 16-groups
            DPPADD(P2r, 0x142, 0xA); DPPADD(P2i, 0x142, 0xA);  // bcast15 -> rows 1,3
            DPPADD(P2r, 0x143, 0xC); DPPADD(P2i, 0x143, 0xC);  // bcast31 -> rows 2,3
            const float sP2r = __int_as_float(__builtin_amdgcn_readlane(__float_as_int(P2r), 63));
            const float sP2i = __int_as_float(__builtin_amdgcn_readlane(__float_as_int(P2i), 63));

            // start new reduction: p = w_n * u[n+2] (w not yet updated this iter)
            const float2 u2 = ubuf[(q + 2) & 7];
            float pr = wr * u2.x - wi * u2.y;
            float pi = wr * u2.y + wi * u2.x;
            DPPADD(pr, 0xB1, 0xF);  DPPADD(pi, 0xB1, 0xF);     // xor1 (quad_perm)
            DPPADD(pr, 0x4E, 0xF);  DPPADD(pi, 0x4E, 0xF);     // xor2 (quad_perm)
            DPPADD(pr, 0x141, 0xF); DPPADD(pi, 0x141, 0xF);    // half_mirror: 8-groups

            // u rotate + deep prefetch (8 iters ahead)
            const float2 un = ubuf[(q + 1) & 7];
            ubuf[(q + 1) & 7] = uin[(size_t)min(n + 9, N_STEPS - 1) * ELEMS + lane];

            // ---- off-chain v_n-derived helpers ----
            const float m2v  = vr * vr + vi * vi;
            const float invv = __builtin_amdgcn_rcpf(m2v + EPS_C);
            const float cvs  = LR_F * invv;
            const float cvr  = vr * cvs, cvi = -vi * cvs;  // LR_F*conj(v)*invv
            const float Rf   = GMAXF * (m2v + EPS_C) * __builtin_amdgcn_rsqf(m2v);

            // ---- serial chain ----
            // z = v*f + b  (this step's output)
            const float zr = vr * fr - vi * fi + br;
            const float zi = vr * fi + vi * fr + bi;
            if (lane == 0) outp[(size_t)n * NDIMS] = make_float2(zr, zi);

            // d = slice(z): nearest odd level, ties to lower (matches argmin first-index)
            float odr = 2.0f * ceilf(zr * HALF_S10) - 1.0f;
            float odi = 2.0f * ceilf(zi * HALF_S10) - 1.0f;
            odr = fminf(3.0f, fmaxf(-3.0f, odr));
            odi = fminf(3.0f, fmaxf(-3.0f, odi));
            const float dr = odr * INV_S10;
            const float di = odi * INV_S10;

            // e = d - z  (= e_f = e_s = e_b)
            const float er = dr - zr, ei = di - zi;

            // e_w = (d - b_n)*psi_n - v_n
            const float dbr = dr - br, dbi = di - bi;
            const float ewr = dbr * psir - dbi * psii - vr;
            const float ewi = dbr * psii + dbi * psir - vi;

            // b update
            br += LR_B * er;
            bi += LR_B * ei;

            // f update: f += fac * (e * LR_F*conj(v)*invv), fac = clip factor
            const float e2  = er * er + ei * ei;
            const float fac = fminf(1.0f, Rf * __builtin_amdgcn_rsqf(e2));
            const float gr  = er * cvr - ei * cvi;
            const float gi  = er * cvi + ei * cvr;
            fr += fac * gr;
            fi += fac * gi;

            // psi for next step: conj(f_{n+1})/|f_{n+1}|
            const float m2f = fr * fr + fi * fi;
            const float rsf = __builtin_amdgcn_rsqf(m2f);
            psir = fr * rsf;
            psii = -fi * rsf;

            // v_{n+1} = P2 + krho2[n-1]*ew_{n-1} + krho1[n]*ew_n
            vr = sP2r + vpr + k1r * ewr - k1i * ewi;
            vi = sP2i + vpi + k1r * ewi + k1i * ewr;

            // carry krho2[n]*ew_n for next iter
            vpr = k2r * ewr - k2i * ewi;
            vpi = k2r * ewi + k2i * ewr;

            // w += (kappa*ew) * conj(u_n)   (gw clip provably inactive: |gw| << 30)
            const float mwr = kap * ewr, mwi = kap * ewi;
            wr += mwr * uc.x + mwi * uc.y;
            wi += mwi * uc.x - mwr * uc.y;

            // rotate
            uc = un;
            redr = pr;
            redi = pi;
        }
    }
}

extern "C" void kernel_launch(void* const* d_in, const int* in_sizes, int n_in,
                              void* d_out, int out_size, void* d_ws, size_t ws_size,
                              hipStream_t stream) {
    const float2* u = (const float2*)d_in[0];
    float4* C = (float4*)d_ws;                                             // 1.6 MB
    float2* D = (float2*)((char*)d_ws + (size_t)N_STEPS * sizeof(float4)); // +0.8 MB
    ddlms_pre<<<(N_STEPS + 3) / 4, 256, 0, stream>>>(u, C, D);
    ddlms_main<<<NDIMS, 64, 0, stream>>>(u, C, D, (float2*)d_out);
}